// Round 8
// baseline (3471.523 us; speedup 1.0000x reference)
//
#include <hip/hip_runtime.h>

// LSTM B=64 T=512 I=512 H=1024 — round 8.
// Round-7 floor was the per-step chain: poll -> 2 serialized h-load RTTs ->
// gate -> ack -> 64 same-line RMW publishes. Fixes:
//  - waves = 8 DISJOINT K-slices (64 x-k + 128 h-k each), computing BOTH
//    m-tiles (B-operand shared, A-operand = register weights per mt):
//    no mt-duplication -> half the coherent IF traffic, half the publishes.
//  - all 16 h b128 coherent loads issued in ONE batch, single vmcnt(0).
//  - publish: 4 sub-counters/quarter (8 adds each, 64B apart); consumers
//    poll a 4-line lane-gather with __all.
//  - h in 4 rotating buffers (reader must lag 3 full steps to race).
//  - 8-source single-phase LDS reduction (pad 17), gate waves 0 (mt0) / 4 (mt1).

typedef short bf16x8 __attribute__((ext_vector_type(8)));
typedef float f32x4  __attribute__((ext_vector_type(4)));
typedef unsigned u32x4 __attribute__((ext_vector_type(4)));

#define BB 64
#define TT 512
#define II 512
#define HH 1024

#define NBLK 256
#define NTHR 512

// ws layout (bytes)
#define WS_CNT_OFF   0                       // 64 counters, 64B apart (memset 8K)
#define WS_HPAKH_OFF 8192                    // u16 [4][HH/8][BB][8] = 512 KB
#define WS_HPAKL_OFF (8192 + 524288)
#define WS_XPAKH_OFF (2 << 20)               // u16 [TT][II/8][BB][8] = 32 MB
#define WS_XPAKL_OFF ((2 << 20) + (32u << 20))

#define HBUF_STRIDE 65536                    // u16 per h buffer (128 rows * 512)
#define XT_STRIDE   32768                    // u16 per timestep of x

__device__ __forceinline__ void atomic_add_rlx(int* p) {
    (void)__hip_atomic_fetch_add(p, 1, __ATOMIC_RELAXED, __HIP_MEMORY_SCOPE_AGENT);
}
__device__ __forceinline__ int load_rlx(const int* p) {
    return __hip_atomic_load(p, __ATOMIC_RELAXED, __HIP_MEMORY_SCOPE_AGENT);
}
__device__ __forceinline__ void store_wt_u16(unsigned short* p, unsigned short v) {
    __hip_atomic_store(p, v, __ATOMIC_RELAXED, __HIP_MEMORY_SCOPE_AGENT);
}

__device__ __forceinline__ float fast_sigmoid(float x) {
    return 1.0f / (1.0f + __expf(-x));
}
__device__ __forceinline__ float fast_tanh(float x) {
    x = fminf(15.0f, fmaxf(-15.0f, x));
    const float e = __expf(2.0f * x);
    return (e - 1.0f) / (e + 1.0f);
}

// fp32 -> bf16 hi + bf16 lo-of-residual (RNE both)
__device__ __forceinline__ void split_bf16(float x, unsigned& hi, unsigned& lo)
{
    unsigned b = __float_as_uint(x);
    hi = (b + 0x7fffu + ((b >> 16) & 1u)) >> 16;
    float r = x - __uint_as_float(hi << 16);
    unsigned bl = __float_as_uint(r);
    lo = (bl + 0x7fffu + ((bl >> 16) & 1u)) >> 16;
}

#define MFMA(A, B, C) __builtin_amdgcn_mfma_f32_16x16x32_bf16((A), (B), (C), 0, 0, 0)

// coherent 16B load, issued WITHOUT wait
__device__ __forceinline__ void issue_coh(const unsigned short* p, u32x4& d)
{
    asm volatile("global_load_dwordx4 %0, %1, off sc0 sc1" : "=v"(d) : "v"(p));
}

// x -> split planes, layout [t][k>>3][b][k&7] u16 per plane
__global__ void __launch_bounds__(256)
transpose_pack_x(const float* __restrict__ x,
                 unsigned short* __restrict__ xH, unsigned short* __restrict__ xL)
{
    __shared__ float tile[64][65];
    const int t   = (int)blockIdx.x;
    const int tid = (int)threadIdx.x;
    const int li  = tid & 63;
    const int w4  = tid >> 6;

    for (int kc = 0; kc < II; kc += 64) {
#pragma unroll
        for (int r = 0; r < 16; ++r) {
            const int b = w4 * 16 + r;
            tile[b][li] = x[((size_t)b * TT + t) * II + kc + li];
        }
        __syncthreads();
#pragma unroll
        for (int half = 0; half < 2; ++half) {
            const int u  = tid + half * 256;      // u = k8*64 + b
            const int k8 = u >> 6, b = u & 63;
            unsigned short oh[8], ol[8];
#pragma unroll
            for (int e = 0; e < 8; ++e) {
                unsigned hi, lo;
                split_bf16(tile[b][k8 * 8 + e], hi, lo);
                oh[e] = (unsigned short)hi;
                ol[e] = (unsigned short)lo;
            }
            const size_t idx = (size_t)t * XT_STRIDE + ((kc >> 3) + k8) * 512 + b * 8;
            *(uint4*)(xH + idx) = *(const uint4*)oh;
            *(uint4*)(xL + idx) = *(const uint4*)ol;
        }
        __syncthreads();
    }
}

__global__ void __launch_bounds__(NTHR, 2)   // <=256 VGPR, 1 block/CU
lstm_mfma(const unsigned short* __restrict__ xH,
          const unsigned short* __restrict__ xL,
          const int*   __restrict__ lens,
          const float* __restrict__ Wih,     // [4H][I]
          const float* __restrict__ Whh,     // [4H][H]
          const float* __restrict__ bih,
          const float* __restrict__ bhh,
          unsigned short* __restrict__ hH,   // [4][H/8][B][8]
          unsigned short* __restrict__ hL,
          int*   __restrict__ cnts,          // [bh][8 quarters][4 subs], 16-int stride
          float* __restrict__ out)           // [B][H]
{
    __shared__ float red[2][2][8][2][16][17];  // [pa][mt][src][nt][bsub][pad17] = 69.6 KB

    const int tid  = (int)threadIdx.x;
    const int l    = tid & 63;
    const int w    = __builtin_amdgcn_readfirstlane(tid >> 6);  // wave 0..7 = K-slice
    const int bsub = l & 15;
    const int q    = l >> 4;                 // quad

    const int jt = (int)blockIdx.x >> 1;     // 0..127, owns j [8jt, 8jt+8)
    const int bh = (int)blockIdx.x & 1;
    const int j0 = jt * 8;

    const int bofs[2] = {(bh * 32 + bsub) * 8, (bh * 32 + 16 + bsub) * 8};

    // ---- weight A-fragments -> registers, both m-tiles (persist across t) ----
    bf16x8 wxh[2][2], wxl[2][2];   // [xi][mt]
    bf16x8 whh[4][2], whl[4][2];   // [hi2][mt]
#pragma unroll
    for (int mt = 0; mt < 2; ++mt) {
        const int row = (l & 3) * HH + j0 + mt * 4 + ((l & 15) >> 2);
#pragma unroll
        for (int xi = 0; xi < 2; ++xi) {
            const float* src = Wih + (size_t)row * II + (2 * w + xi) * 32 + q * 8;
            const float4 w0 = *(const float4*)src;
            const float4 w1 = *(const float4*)(src + 4);
            const float wf[8] = {w0.x, w0.y, w0.z, w0.w, w1.x, w1.y, w1.z, w1.w};
#pragma unroll
            for (int e = 0; e < 8; ++e) {
                unsigned hi, lo;
                split_bf16(wf[e], hi, lo);
                wxh[xi][mt][e] = (short)hi;
                wxl[xi][mt][e] = (short)lo;
            }
        }
#pragma unroll
        for (int hi2 = 0; hi2 < 4; ++hi2) {
            const float* src = Whh + (size_t)row * HH + (4 * w + hi2) * 32 + q * 8;
            const float4 w0 = *(const float4*)src;
            const float4 w1 = *(const float4*)(src + 4);
            const float wf[8] = {w0.x, w0.y, w0.z, w0.w, w1.x, w1.y, w1.z, w1.w};
#pragma unroll
            for (int e = 0; e < 8; ++e) {
                unsigned hi, lo;
                split_bf16(wf[e], hi, lo);
                whh[hi2][mt][e] = (short)hi;
                whl[hi2][mt][e] = (short)lo;
            }
        }
    }

    // ---- gate-wave state: wave 0 owns mt0 (j0..j0+3), wave 4 owns mt1 ----
    const int gw = (w == 0) ? 0 : (w == 4) ? 1 : -1;
    float bias[4], c[2] = {0.f, 0.f}, lasth[2] = {0.f, 0.f};
    int len[2] = {0, 0};
    const int jlow  = (gw >= 0) ? gw * 4 + q : 0;
    const int jcell = j0 + jlow;
    int* prodc = cnts + ((bh * 8 + (jt >> 4)) * 4 + ((jt >> 2) & 3)) * 16;

    if (gw >= 0) {
#pragma unroll
        for (int g = 0; g < 4; ++g)
            bias[g] = bih[g * HH + jcell] + bhh[g * HH + jcell];
#pragma unroll
        for (int nt = 0; nt < 2; ++nt) {
            const int b = bh * 32 + nt * 16 + bsub;
            len[nt] = lens[b];
            store_wt_u16(hH + (size_t)jt * 512 + b * 8 + jlow, 0);   // h_0, buf 0
            store_wt_u16(hL + (size_t)jt * 512 + b * 8 + jlow, 0);
        }
        asm volatile("s_waitcnt vmcnt(0)" ::: "memory");
        if (l == 0) atomic_add_rlx(prodc);   // init publish: each sub -> 8
    }

    const int* pollp = cnts + ((bh * 8 + w) * 4 + (l & 3)) * 16;

    for (int t = 0; t < TT; ++t) {
        // ---- x-part: plain cached b128 loads (L2-resident, never invalidated) ----
        f32x4 s0[2][2], s1[2][2];            // [mt][nt], 2 streams
#pragma unroll
        for (int mt = 0; mt < 2; ++mt)
#pragma unroll
            for (int nt = 0; nt < 2; ++nt)
                s0[mt][nt] = s1[mt][nt] = (f32x4){0.f, 0.f, 0.f, 0.f};
        {
            const unsigned short* xh = xH + (size_t)t * XT_STRIDE;
            const unsigned short* xl = xL + (size_t)t * XT_STRIDE;
#pragma unroll
            for (int xi = 0; xi < 2; ++xi) {
                const int idx = ((2 * w + xi) * 4 + q) * 512;
#pragma unroll
                for (int nt = 0; nt < 2; ++nt) {
                    const bf16x8 ahi = *(const bf16x8*)(xh + idx + bofs[nt]);
                    const bf16x8 alo = *(const bf16x8*)(xl + idx + bofs[nt]);
#pragma unroll
                    for (int mt = 0; mt < 2; ++mt) {
                        s0[mt][nt] = MFMA(wxh[xi][mt], ahi, s0[mt][nt]);
                        s1[mt][nt] = MFMA(wxh[xi][mt], alo, s1[mt][nt]);
                        s1[mt][nt] = MFMA(wxl[xi][mt], ahi, s1[mt][nt]);
                    }
                }
            }
        }

        // ---- poll: my K-slice's 4 sub-counters (4-line lane gather) ----
        {
            const int need = 8 * (t + 1);
            while (true) {
                const int v = load_rlx(pollp);
                if (__all(v >= need)) break;
                __builtin_amdgcn_s_sleep(1);
            }
            asm volatile("" ::: "memory");
        }

        // ---- h-part: 16 coherent b128 loads, ONE batch, ONE wait ----
        const unsigned short* hph = hH + (size_t)(t & 3) * HBUF_STRIDE;
        const unsigned short* hpl = hL + (size_t)(t & 3) * HBUF_STRIDE;
        u32x4 fh[4][2], fl[4][2];
#pragma unroll
        for (int hi2 = 0; hi2 < 4; ++hi2) {
            const int idx = ((4 * w + hi2) * 4 + q) * 512;
#pragma unroll
            for (int nt = 0; nt < 2; ++nt) {
                issue_coh(hph + idx + bofs[nt], fh[hi2][nt]);
                issue_coh(hpl + idx + bofs[nt], fl[hi2][nt]);
            }
        }
        asm volatile("s_waitcnt vmcnt(0)"
            : "+v"(fh[0][0]), "+v"(fh[0][1]), "+v"(fh[1][0]), "+v"(fh[1][1]),
              "+v"(fh[2][0]), "+v"(fh[2][1]), "+v"(fh[3][0]), "+v"(fh[3][1]),
              "+v"(fl[0][0]), "+v"(fl[0][1]), "+v"(fl[1][0]), "+v"(fl[1][1]),
              "+v"(fl[2][0]), "+v"(fl[2][1]), "+v"(fl[3][0]), "+v"(fl[3][1])
            :: "memory");
#pragma unroll
        for (int hi2 = 0; hi2 < 4; ++hi2) {
#pragma unroll
            for (int nt = 0; nt < 2; ++nt) {
                const bf16x8 ahi = __builtin_bit_cast(bf16x8, fh[hi2][nt]);
                const bf16x8 alo = __builtin_bit_cast(bf16x8, fl[hi2][nt]);
#pragma unroll
                for (int mt = 0; mt < 2; ++mt) {
                    s0[mt][nt] = MFMA(whh[hi2][mt], ahi, s0[mt][nt]);
                    s1[mt][nt] = MFMA(whh[hi2][mt], alo, s1[mt][nt]);
                    s1[mt][nt] = MFMA(whl[hi2][mt], ahi, s1[mt][nt]);
                }
            }
        }

        // ---- 8-source single-phase reduction ----
        const int pa = t & 1;
#pragma unroll
        for (int mt = 0; mt < 2; ++mt)
#pragma unroll
            for (int nt = 0; nt < 2; ++nt)
#pragma unroll
                for (int i = 0; i < 4; ++i)
                    red[pa][mt][w][nt][bsub][4 * q + i] = s0[mt][nt][i] + s1[mt][nt][i];
        __syncthreads();

        // ---- gate math (waves 0 and 4), h store, ack, publish ----
        if (gw >= 0) {
            unsigned short* dsth = hH + (size_t)((t + 1) & 3) * HBUF_STRIDE + jt * 512;
            unsigned short* dstl = hL + (size_t)((t + 1) & 3) * HBUF_STRIDE + jt * 512;
#pragma unroll
            for (int nt = 0; nt < 2; ++nt) {
                float g4[4];
#pragma unroll
                for (int i = 0; i < 4; ++i) {
                    float s = bias[i];
#pragma unroll
                    for (int src = 0; src < 8; ++src)
                        s += red[pa][gw][src][nt][bsub][4 * q + i];
                    g4[i] = s;
                }
                const float ig = fast_sigmoid(g4[0]);
                const float fg = fast_sigmoid(g4[1]);
                const float gg = fast_tanh(g4[2]);
                const float og = fast_sigmoid(g4[3]);
                c[nt] = fg * c[nt] + ig * gg;
                const float h = og * fast_tanh(c[nt]);
                unsigned hi, lo;
                split_bf16(h, hi, lo);
                const int b = bh * 32 + nt * 16 + bsub;
                store_wt_u16(dsth + b * 8 + jlow, (unsigned short)hi);
                store_wt_u16(dstl + b * 8 + jlow, (unsigned short)lo);
                if (t == len[nt] - 1) lasth[nt] = h;
            }
            asm volatile("s_waitcnt vmcnt(0)" ::: "memory");  // h stores visible
            if (l == 0) atomic_add_rlx(prodc);                // publish h_{t+1}
        }
    }

    // ---- epilogue ----
    if (gw >= 0) {
#pragma unroll
        for (int nt = 0; nt < 2; ++nt) {
            const int b = bh * 32 + nt * 16 + bsub;
            out[(size_t)b * HH + jcell] = lasth[nt];
        }
    }
}

extern "C" void kernel_launch(void* const* d_in, const int* in_sizes, int n_in,
                              void* d_out, int out_size, void* d_ws, size_t ws_size,
                              hipStream_t stream)
{
    const float* seq  = (const float*)d_in[0];
    const int*   lens = (const int*)  d_in[1];
    const float* Wih  = (const float*)d_in[2];
    const float* Whh  = (const float*)d_in[3];
    const float* bih  = (const float*)d_in[4];
    const float* bhh  = (const float*)d_in[5];
    float* out = (float*)d_out;

    char* ws = (char*)d_ws;
    int*            cnts = (int*)           (ws + WS_CNT_OFF);
    unsigned short* hH   = (unsigned short*)(ws + WS_HPAKH_OFF);
    unsigned short* hL   = (unsigned short*)(ws + WS_HPAKL_OFF);
    unsigned short* xH   = (unsigned short*)(ws + WS_XPAKH_OFF);
    unsigned short* xL   = (unsigned short*)(ws + WS_XPAKL_OFF);

    hipMemsetAsync(cnts, 0, 8192, stream);   // monotonic counters start at 0
    transpose_pack_x<<<dim3(TT), dim3(256), 0, stream>>>(seq, xH, xL);
    lstm_mfma<<<dim3(NBLK), dim3(NTHR), 0, stream>>>(xH, xL, lens, Wih, Whh, bih, bhh,
                                                     hH, hL, cnts, out);
}